// Round 6
// baseline (3307.646 us; speedup 1.0000x reference)
//
#include <hip/hip_runtime.h>
#include <hip/hip_bf16.h>

typedef unsigned short u16;
typedef unsigned int u32;
typedef unsigned long long u64;
typedef signed char i8;
using bf16x8 = __attribute__((ext_vector_type(8))) short;
using f32x4  = __attribute__((ext_vector_type(4))) float;
using i32x4  = __attribute__((ext_vector_type(4))) int;

__device__ inline u16 f2bf(float f) {
  union { float f; unsigned u; } v; v.f = f;
  unsigned u = v.u;
  unsigned r = (u + 0x7FFFu + ((u >> 16) & 1u)) >> 16;
  return (u16)r;
}
__device__ inline float bf2f(u16 b) {
  union { unsigned u; float f; } v; v.u = ((unsigned)b) << 16;
  return v.f;
}
__device__ inline float sigf(float x) { return 1.0f / (1.0f + __expf(-x)); }
__device__ inline float tanhfast(float x) { return 1.0f - 2.0f / (__expf(2.0f * x) + 1.0f); }

// ---------------- prep kernels ----------------

__global__ void cvt_bf16(const float* __restrict__ in, u16* __restrict__ out, int n) {
  for (int i = blockIdx.x * 256 + threadIdx.x; i < n; i += gridDim.x * 256)
    out[i] = f2bf(in[i]);
}

// G[j][c] = sum_i fc2w[i*256+j] * Avec[i][c]
__global__ __launch_bounds__(256) void gmat_kernel(const float* __restrict__ fc2w,
                                                   const float* __restrict__ dw,
                                                   float* __restrict__ G) {
  int j = threadIdx.x;
  float g0 = 0.f, g1 = 0.f, g2 = 0.f;
  for (int i = 0; i < 256; ++i) {
    float a0 = dw[i * 9 + 7] - dw[i * 9 + 5];
    float a1 = dw[i * 9 + 2] - dw[i * 9 + 6];
    float a2 = dw[i * 9 + 3] - dw[i * 9 + 1];
    float w = fc2w[i * 256 + j];
    g0 += w * a0; g1 += w * a1; g2 += w * a2;
  }
  G[j * 3 + 0] = g0; G[j * 3 + 1] = g1; G[j * 3 + 2] = g2;
}

// W_hh [1024][256] fp32 -> i8 with per-row scale
__global__ __launch_bounds__(256) void quant_whh(const float* __restrict__ W,
                                                 i8* __restrict__ Wq,
                                                 float* __restrict__ sWq) {
  int w = threadIdx.x >> 6, lane = threadIdx.x & 63;
  int row = blockIdx.x * 4 + w;
  float4 v = *(const float4*)(W + (size_t)row * 256 + lane * 4);
  float m = fmaxf(fmaxf(fabsf(v.x), fabsf(v.y)), fmaxf(fabsf(v.z), fabsf(v.w)));
#pragma unroll
  for (int off = 1; off < 64; off <<= 1) m = fmaxf(m, __shfl_xor(m, off));
  float inv = m > 0.f ? 127.f / m : 0.f;
  int q0 = __float2int_rn(v.x * inv), q1 = __float2int_rn(v.y * inv);
  int q2 = __float2int_rn(v.z * inv), q3 = __float2int_rn(v.w * inv);
  u32 pk = (q0 & 255) | ((q1 & 255) << 8) | ((q2 & 255) << 16) | ((q3 & 255) << 24);
  *(u32*)(Wq + (size_t)row * 256 + lane * 4) = pk;
  if (lane == 0) sWq[row] = m * (1.f / 127.f);
}

// ---------------- fc1_1 (chunked over T) ----------------

__global__ __launch_bounds__(256) void fc1_kernel(const float* __restrict__ X,
                                                  const float* __restrict__ W1,
                                                  const float* __restrict__ b1,
                                                  u16* __restrict__ H1, int t0, int tcl2) {
  __shared__ float w1s[256 * 9];
  int tid = threadIdx.x;
  for (int idx = tid; idx < 2048; idx += 256)
    w1s[(idx >> 3) * 9 + (idx & 7)] = W1[idx];
  __syncthreads();
  float wreg[8];
#pragma unroll
  for (int i = 0; i < 8; ++i) wreg[i] = w1s[tid * 9 + i];
  float bb = b1[tid];
  int Tc = 1 << tcl2;
  int row0 = blockIdx.x * 64;
  for (int r = 0; r < 64; ++r) {
    int rl = row0 + r;
    int b = rl >> tcl2, tp = rl & (Tc - 1);
    const float4* xr = (const float4*)(X + ((size_t)b * 2048 + t0 + tp) * 8);
    float4 xa = xr[0], xb = xr[1];
    float acc = bb + xa.x * wreg[0] + xa.y * wreg[1] + xa.z * wreg[2] + xa.w * wreg[3]
                   + xb.x * wreg[4] + xb.y * wreg[5] + xb.z * wreg[6] + xb.w * wreg[7];
    H1[(size_t)rl * 256 + tid] = f2bf(fmaxf(acc, 0.f));
  }
}

// ---------------- bf16 MFMA GEMM, K=256 ----------------

__global__ __launch_bounds__(256) void gemm_k256(const u16* __restrict__ A,
                                                 const u16* __restrict__ Bw,
                                                 const float* __restrict__ bias0,
                                                 const float* __restrict__ bias1,
                                                 u16* __restrict__ out, int N, int relu) {
  int tid = threadIdx.x;
  int lane = tid & 63, wv = tid >> 6;
  int lr = lane & 15, lk = lane >> 4;
  int nblk = N >> 6;
  int mb = blockIdx.x / nblk, nb = blockIdx.x - mb * nblk;
  int R0 = mb * 128 + (wv >> 1) * 64;
  int C0 = nb * 64 + (wv & 1) * 32;
  f32x4 acc[4][2];
#pragma unroll
  for (int mt = 0; mt < 4; ++mt)
#pragma unroll
    for (int nt = 0; nt < 2; ++nt) acc[mt][nt] = (f32x4){0.f, 0.f, 0.f, 0.f};
#pragma unroll
  for (int kk = 0; kk < 8; ++kk) {
    int ko = 32 * kk + 8 * lk;
    bf16x8 af[4], bfr[2];
#pragma unroll
    for (int mt = 0; mt < 4; ++mt)
      af[mt] = *(const bf16x8*)(A + (size_t)(R0 + 16 * mt + lr) * 256 + ko);
#pragma unroll
    for (int nt = 0; nt < 2; ++nt)
      bfr[nt] = *(const bf16x8*)(Bw + (size_t)(C0 + 16 * nt + lr) * 256 + ko);
#pragma unroll
    for (int mt = 0; mt < 4; ++mt)
#pragma unroll
      for (int nt = 0; nt < 2; ++nt)
        acc[mt][nt] = __builtin_amdgcn_mfma_f32_16x16x32_bf16(af[mt], bfr[nt], acc[mt][nt], 0, 0, 0);
  }
#pragma unroll
  for (int nt = 0; nt < 2; ++nt) {
    int col = C0 + 16 * nt + lr;
    float bs = bias0[col] + (bias1 ? bias1[col] : 0.f);
#pragma unroll
    for (int mt = 0; mt < 4; ++mt) {
#pragma unroll
      for (int r = 0; r < 4; ++r) {
        int row = R0 + 16 * mt + 4 * lk + r;
        float v = acc[mt][nt][r] + bs;
        if (relu) v = fmaxf(v, 0.f);
        out[(size_t)row * N + col] = f2bf(v);
      }
    }
  }
}

// ---------------- persistent LSTM v6: gate-aligned waves, 1 barrier/step ----
// 64 blocks x 1024 thr (16 waves). Block = one batch; full i8 W_hh in
// VGPR/AGPR fragments. Wave w owns units [16w,16w+16): cols {g*256+16w+lr}.
// After 16 MFMAs every lane holds all 4 gate preacts of its unit (broadcast-A
// -> identical C rows) -> in-register update, no gates LDS, no mid barrier.
// h_i8 double-buffered in LDS; one barrier per step. Per-wave omega partials
// to global (summed by wred16).
__global__ __launch_bounds__(1024, 1) void lstm_kernel(const u16* __restrict__ XGb,
                                                       const i8* __restrict__ Wq,
                                                       const float* __restrict__ sWq,
                                                       const float* __restrict__ G,
                                                       float* __restrict__ part,
                                                       float* __restrict__ cstate,
                                                       float* __restrict__ hstate,
                                                       int t0, int Tc) {
  __shared__ i8 hb[2][320];

  int tid = threadIdx.x;
  int w = tid >> 6, lane = tid & 63;
  int lr = lane & 15, lk = lane >> 4;
  int b = blockIdx.x;
  int u = 16 * w + lr;  // this lane's hidden unit (4 redundant copies over lk)

  // weight fragments: wf[g][kb] = Wq[(g*256+u)*256 + 64*kb + 16*lk ..+16)
  i32x4 wf[4][4];
  float swf[4];
#pragma unroll
  for (int g = 0; g < 4; ++g) {
    int col = g * 256 + u;
#pragma unroll
    for (int kb = 0; kb < 4; ++kb)
      wf[g][kb] = *(const i32x4*)(Wq + (size_t)col * 256 + 64 * kb + 16 * lk);
    swf[g] = sWq[col] * (1.f / 127.f);
  }
  float Gr0 = G[u * 3 + 0], Gr1 = G[u * 3 + 1], Gr2 = G[u * 3 + 2];

  float cst = 0.f, hp = 0.f;
  if (t0 > 0) {
    cst = cstate[b * 256 + u];
    hp = hstate[b * 256 + u];
  }
  if (lk == 0) hb[0][u] = (t0 > 0) ? (i8)__float2int_rn(hp * 127.f) : (i8)0;

  // x prefetch (registers, one step ahead)
  const u16* xrow = XGb + (size_t)b * Tc * 1024;
  u16 xn0 = xrow[u], xn1 = xrow[256 + u], xn2 = xrow[512 + u], xn3 = xrow[768 + u];
  float* pp = part + ((size_t)b * Tc * 16 + w) * 3;
  __syncthreads();

  for (int tp = 0; tp < Tc; ++tp) {
    u16 xc0 = xn0, xc1 = xn1, xc2 = xn2, xc3 = xn3;
    if (tp + 1 < Tc) {
      xrow += 1024;
      xn0 = xrow[u]; xn1 = xrow[256 + u]; xn2 = xrow[512 + u]; xn3 = xrow[768 + u];
    }
    const i8* hcur = hb[tp & 1];
    i32x4 af[4];
#pragma unroll
    for (int kb = 0; kb < 4; ++kb)
      af[kb] = *(const i32x4*)&hcur[64 * kb + 16 * lk];
    i32x4 acc[4];
#pragma unroll
    for (int g = 0; g < 4; ++g) acc[g] = (i32x4){0, 0, 0, 0};
#pragma unroll
    for (int kb = 0; kb < 4; ++kb)
#pragma unroll
      for (int g = 0; g < 4; ++g)
        acc[g] = __builtin_amdgcn_mfma_i32_16x16x64_i8(af[kb], wf[g][kb], acc[g], 0, 0, 0);
    // every lane: all 4 gate preacts of unit u
    float pi = bf2f(xc0) + (float)acc[0][0] * swf[0];
    float pf = bf2f(xc1) + (float)acc[1][0] * swf[1];
    float pg = bf2f(xc2) + (float)acc[2][0] * swf[2];
    float po = bf2f(xc3) + (float)acc[3][0] * swf[3];
    cst = sigf(pf) * cst + sigf(pi) * tanhfast(pg);
    float hn = sigf(po) * tanhfast(cst);
    float dd = hn - hp; hp = hn;
    if (lk == 0) hb[(tp + 1) & 1][u] = (i8)__float2int_rn(hn * 127.f);
    float wa0 = dd * Gr0, wa1 = dd * Gr1, wa2 = dd * Gr2;
#pragma unroll
    for (int off = 1; off < 16; off <<= 1) {
      wa0 += __shfl_xor(wa0, off);
      wa1 += __shfl_xor(wa1, off);
      wa2 += __shfl_xor(wa2, off);
    }
    if (lane == 0) { pp[0] = wa0; pp[1] = wa1; pp[2] = wa2; }
    pp += 48;
    __syncthreads();
  }
  if (lk == 0) {
    cstate[b * 256 + u] = cst;
    hstate[b * 256 + u] = hp;
  }
}

// ---------------- sum 16 per-wave partials -> wpart[b][gt-1][c] ----------------
__global__ __launch_bounds__(192) void wred16(const float* __restrict__ part,
                                              float* __restrict__ wpart,
                                              int t0, int Tc) {
  int b = blockIdx.x;
  int tp = blockIdx.y * 64 + threadIdx.x;
  int c = threadIdx.y;
  int gt = t0 + tp;
  const float* p = part + ((size_t)b * Tc + tp) * 48 + c;
  float s = 0.f;
#pragma unroll
  for (int w = 0; w < 16; ++w) s += p[w * 3];
  if (gt >= 1) wpart[((size_t)b * 2047 + (gt - 1)) * 3 + c] = s;
}

// ---------------- rotation prefix scan ----------------

__device__ inline void mat3mul(float* __restrict__ o, const float* a, const float* b) {
#pragma unroll
  for (int i = 0; i < 3; ++i)
#pragma unroll
    for (int j = 0; j < 3; ++j)
      o[i * 3 + j] = a[i * 3 + 0] * b[0 * 3 + j] + a[i * 3 + 1] * b[1 * 3 + j] + a[i * 3 + 2] * b[2 * 3 + j];
}

__device__ inline void rodrigues(float w1, float w2, float w3, float* R) {
  float t2 = w1 * w1 + w2 * w2 + w3 * w3;
  float A, Bc;
  if (t2 < 1e-8f) {
    A = 1.f - t2 * (1.f / 6.f);
    Bc = 0.5f - t2 * (1.f / 24.f);
  } else {
    float th = sqrtf(t2);
    A = __sinf(th) / th;
    Bc = (1.f - __cosf(th)) / t2;
  }
  float c_ = 1.f - Bc * t2;
  R[0] = c_ + Bc * w1 * w1; R[1] = Bc * w1 * w2 - A * w3; R[2] = Bc * w1 * w3 + A * w2;
  R[3] = Bc * w1 * w2 + A * w3; R[4] = c_ + Bc * w2 * w2; R[5] = Bc * w2 * w3 - A * w1;
  R[6] = Bc * w1 * w3 - A * w2; R[7] = Bc * w2 * w3 + A * w1; R[8] = c_ + Bc * w3 * w3;
}

__global__ __launch_bounds__(256) void rotscan_kernel(const float* __restrict__ wpart,
                                                      float* __restrict__ out) {
  __shared__ float buf[2][256][9];
  int b = blockIdx.x, tid = threadIdx.x;
  const float* w0 = wpart + (size_t)b * 2047 * 3;
  float R[8][9];
  float C[9] = {1, 0, 0, 0, 1, 0, 0, 0, 1};
#pragma unroll
  for (int s = 0; s < 8; ++s) {
    int idx = tid * 8 + s;
    float wx = 0.f, wy = 0.f, wz = 0.f;
    if (idx < 2047) {
      wx = w0[idx * 3 + 0];
      wy = w0[idx * 3 + 1];
      wz = w0[idx * 3 + 2];
    }
    rodrigues(wx, wy, wz, R[s]);
    float T_[9];
    mat3mul(T_, C, R[s]);
#pragma unroll
    for (int e = 0; e < 9; ++e) C[e] = T_[e];
  }
#pragma unroll
  for (int e = 0; e < 9; ++e) buf[0][tid][e] = C[e];
  __syncthreads();
  int p = 0;
  for (int d = 1; d < 256; d <<= 1) {
    float L[9];
    if (tid >= d) {
      mat3mul(L, buf[p][tid - d], buf[p][tid]);
    } else {
#pragma unroll
      for (int e = 0; e < 9; ++e) L[e] = buf[p][tid][e];
    }
#pragma unroll
    for (int e = 0; e < 9; ++e) buf[p ^ 1][tid][e] = L[e];
    __syncthreads();
    p ^= 1;
  }
  float P[9];
  if (tid == 0) {
    P[0] = 1; P[1] = 0; P[2] = 0; P[3] = 0; P[4] = 1; P[5] = 0; P[6] = 0; P[7] = 0; P[8] = 1;
  } else {
#pragma unroll
    for (int e = 0; e < 9; ++e) P[e] = buf[p][tid - 1][e];
  }
#pragma unroll
  for (int s = 0; s < 8; ++s) {
    float Q[9];
    mat3mul(Q, P, R[s]);
#pragma unroll
    for (int e = 0; e < 9; ++e) P[e] = Q[e];
    int idx = tid * 8 + s;
    if (idx < 2047) {
      size_t o = ((size_t)b * 2047 + idx) * 3;
      out[o + 0] = P[2]; out[o + 1] = P[5]; out[o + 2] = P[8];
    }
  }
}

// ---------------- launch ----------------

extern "C" void kernel_launch(void* const* d_in, const int* in_sizes, int n_in,
                              void* d_out, int out_size, void* d_ws, size_t ws_size,
                              hipStream_t stream) {
  const float* X    = (const float*)d_in[0];
  const float* w1   = (const float*)d_in[1];
  const float* b1   = (const float*)d_in[2];
  const float* w2   = (const float*)d_in[3];
  const float* b2   = (const float*)d_in[4];
  const float* Wih  = (const float*)d_in[5];
  const float* Whh  = (const float*)d_in[6];
  const float* bih  = (const float*)d_in[7];
  const float* bhh  = (const float*)d_in[8];
  const float* fc2w = (const float*)d_in[9];
  const float* devw = (const float*)d_in[11];
  float* out = (float*)d_out;

  char* ws = (char*)d_ws;
  size_t off = 0;
  auto take = [&](size_t bytes) { size_t p = off; off = (off + bytes + 255) & ~255ULL; return p; };
  size_t oW2b   = take((size_t)256 * 256 * 2);
  size_t oWIHb  = take((size_t)1024 * 256 * 2);
  size_t oWq    = take((size_t)1024 * 256);
  size_t osWq   = take((size_t)1024 * 4);
  size_t oG     = take((size_t)256 * 3 * 4);
  size_t oWPART = take((size_t)64 * 2047 * 3 * 4);
  size_t oCST   = take((size_t)64 * 256 * 4);
  size_t oHST   = take((size_t)64 * 256 * 4);
  size_t fixed = off;

  // per-t bytes: H1 32768 + Y2 32768 + XGb 131072 + part 12288 = 208896
  int Tc = 2048, tcl2 = 11;
  while (Tc > 64 && fixed + (size_t)Tc * 208896 + 4096 > ws_size) { Tc >>= 1; --tcl2; }
  if (fixed + (size_t)Tc * 208896 + 4096 > ws_size) return;

  size_t oH1  = take((size_t)64 * Tc * 256 * 2);
  size_t oY2  = take((size_t)64 * Tc * 256 * 2);
  size_t oXGb = take((size_t)64 * Tc * 1024 * 2);
  size_t oPRT = take((size_t)64 * Tc * 16 * 3 * 4);

  u16* W2b     = (u16*)(ws + oW2b);
  u16* WIHb    = (u16*)(ws + oWIHb);
  i8* Wq       = (i8*)(ws + oWq);
  float* sWq   = (float*)(ws + osWq);
  float* G     = (float*)(ws + oG);
  float* WPART = (float*)(ws + oWPART);
  float* CST   = (float*)(ws + oCST);
  float* HST   = (float*)(ws + oHST);
  u16* H1      = (u16*)(ws + oH1);
  u16* Y2      = (u16*)(ws + oY2);
  u16* XGb     = (u16*)(ws + oXGb);
  float* PRT   = (float*)(ws + oPRT);

  cvt_bf16<<<dim3(64), dim3(256), 0, stream>>>(w2, W2b, 256 * 256);
  cvt_bf16<<<dim3(256), dim3(256), 0, stream>>>(Wih, WIHb, 1024 * 256);
  quant_whh<<<dim3(256), dim3(256), 0, stream>>>(Whh, Wq, sWq);
  gmat_kernel<<<dim3(1), dim3(256), 0, stream>>>(fc2w, devw, G);

  int NC = 2048 / Tc;
  int mb = (64 * Tc) / 128;
  for (int c = 0; c < NC; ++c) {
    int t0 = c * Tc;
    fc1_kernel<<<dim3(Tc), dim3(256), 0, stream>>>(X, w1, b1, H1, t0, tcl2);
    gemm_k256<<<dim3(mb * 4), dim3(256), 0, stream>>>(H1, W2b, b2, (const float*)nullptr, Y2, 256, 1);
    gemm_k256<<<dim3(mb * 16), dim3(256), 0, stream>>>(Y2, WIHb, bih, bhh, XGb, 1024, 0);
    lstm_kernel<<<dim3(64), dim3(1024), 0, stream>>>(XGb, Wq, sWq, G, PRT, CST, HST, t0, Tc);
    wred16<<<dim3(64, Tc / 64), dim3(64, 3), 0, stream>>>(PRT, WPART, t0, Tc);
  }
  rotscan_kernel<<<dim3(64), dim3(256), 0, stream>>>(WPART, out);
}